// Round 10
// baseline (789.424 us; speedup 1.0000x reference)
//
#include <hip/hip_runtime.h>

typedef short s8v __attribute__((ext_vector_type(8)));
typedef float f4v __attribute__((ext_vector_type(4)));

__device__ __forceinline__ unsigned short f2bf(float x) {
  union { float f; unsigned u; } v; v.f = x;
  unsigned r = v.u + 0x7fffu + ((v.u >> 16) & 1u);
  return (unsigned short)(r >> 16);
}
__device__ __forceinline__ float bf2f(unsigned u16) {
  union { unsigned u; float f; } v; v.u = u16 << 16;
  return v.f;
}
__device__ __forceinline__ s8v as_s8(int4 v) { union { int4 i; s8v s; } u; u.i = v; return u.s; }
__device__ __forceinline__ f4v as_f4(int4 v) { union { int4 i; f4v f; } u; u.i = v; return u.f; }
__device__ __forceinline__ int4 as_i4(f4v v) { union { f4v f; int4 i; } u; u.f = v; return u.i; }

// ---------------- prep: bf16 casts + weight reorg + accum zero ----------------
__global__ __launch_bounds__(256) void prep_kernel(
    const float* __restrict__ q, const float* __restrict__ k,
    const float* __restrict__ w1, const float* __restrict__ w2, const float* __restrict__ w3,
    unsigned short* __restrict__ Qb, unsigned short* __restrict__ Kb,
    unsigned short* __restrict__ W1, unsigned short* __restrict__ W2,
    unsigned short* __restrict__ W3, float* __restrict__ accum) {
  int idx = blockIdx.x * 256 + threadIdx.x;
  const int NQ = 2048 * 512;
  if (idx < NQ) { Qb[idx] = f2bf(q[idx]); return; }
  idx -= NQ;
  if (idx < NQ) { Kb[idx] = f2bf(k[idx]); return; }
  idx -= NQ;
  if (idx < 3072) {                      // W1p [3 j][32 m][32 k]; k<16: dy=2j taps, k>=16: dy=2j+1
    int j = idx >> 10, m = (idx >> 5) & 31, kk = idx & 31;
    int half = kk >> 4, kl = kk & 15, dy = 2 * j + half;
    float v = 0.f;
    if (m < 30 && kl < 10 && dy < 5) v = w1[m * 50 + (kl & 1) * 25 + dy * 5 + (kl >> 1)];
    W1[idx] = f2bf(v); return;
  }
  idx -= 3072;
  if (idx < 25600) {                     // W2 [5 dy][32 m][160 kk], kk = dx*32 + c
    int dy = idx / 5120, r = idx - dy * 5120, m = r / 160, kk = r - m * 160;
    int c = kk & 31, dx = kk >> 5;
    float v = 0.f;
    if (m < 30 && c < 30) v = w2[m * 750 + c * 25 + dy * 5 + dx];
    W2[idx] = f2bf(v); return;
  }
  idx -= 25600;
  if (idx < 288) {                       // W3 [9 dd=dy*3+dx][32 c]
    int dd = idx >> 5, c = idx & 31;
    float v = (c < 30) ? w3[c * 9 + dd] : 0.f;
    W3[idx] = f2bf(v); return;
  }
  idx -= 288;
  if (idx == 0) *accum = 0.f;
}

// ---------------- row norms ----------------
__global__ __launch_bounds__(256) void norms_kernel(
    const float* __restrict__ q, const float* __restrict__ k,
    float* __restrict__ nq, float* __restrict__ nk) {
  int wv = threadIdx.x >> 6, l = threadIdx.x & 63;
  int row = blockIdx.x * 4 + wv;
  const float* src = (row < 2048) ? (q + row * 512) : (k + (row - 2048) * 512);
  float s = 0.f;
  for (int i = l; i < 512; i += 64) { float v = src[i]; s += v * v; }
  for (int off = 32; off; off >>= 1) s += __shfl_xor(s, off);
  if (l == 0) { if (row < 2048) nq[row] = s; else nk[row - 2048] = s; }
}

// ---------------- D = cdist GEMM (bf16 MFMA cross-term, fp32 norms) ----------------
__global__ __launch_bounds__(256) void dgemm_kernel(
    const unsigned short* __restrict__ Qb, const unsigned short* __restrict__ Kb,
    const float* __restrict__ nq, const float* __restrict__ nk,
    float* __restrict__ Dout) {
  __shared__ int4 sm[2 * 128 * 9];
  const int t = threadIdx.x;
  const int bm = blockIdx.x, bn = blockIdx.y;
  const int wv = t >> 6, l = t & 63;
  const int m0 = (wv & 1) * 64, n0 = (wv >> 1) * 64;
  const int l15 = l & 15, q4 = l >> 4;
  f4v acc[4][4] = {};
  const int4* Qg = (const int4*)Qb;
  const int4* Kg = (const int4*)Kb;
  for (int kt = 0; kt < 8; ++kt) {
    __syncthreads();
#pragma unroll
    for (int i = 0; i < 4; ++i) {
      int c = t + i * 256;
      int row = c >> 3, kq = c & 7;
      sm[row * 9 + kq]        = Qg[(bm * 128 + row) * 64 + kt * 8 + kq];
      sm[1152 + row * 9 + kq] = Kg[(bn * 128 + row) * 64 + kt * 8 + kq];
    }
    __syncthreads();
#pragma unroll
    for (int s = 0; s < 2; ++s) {
      s8v af[4], bfr[4];
#pragma unroll
      for (int mt = 0; mt < 4; ++mt)
        af[mt] = as_s8(sm[(m0 + mt * 16 + l15) * 9 + s * 4 + q4]);
#pragma unroll
      for (int nt = 0; nt < 4; ++nt)
        bfr[nt] = as_s8(sm[1152 + (n0 + nt * 16 + l15) * 9 + s * 4 + q4]);
#pragma unroll
      for (int mt = 0; mt < 4; ++mt)
#pragma unroll
        for (int nt = 0; nt < 4; ++nt)
          acc[mt][nt] = __builtin_amdgcn_mfma_f32_16x16x32_bf16(af[mt], bfr[nt], acc[mt][nt], 0, 0, 0);
    }
  }
  float nkv[4];
#pragma unroll
  for (int nt = 0; nt < 4; ++nt) nkv[nt] = nk[bn * 128 + n0 + nt * 16 + l15];
#pragma unroll
  for (int mt = 0; mt < 4; ++mt)
#pragma unroll
    for (int reg = 0; reg < 4; ++reg) {
      int gr = bm * 128 + m0 + mt * 16 + q4 * 4 + reg;
      float nqv = nq[gr];
#pragma unroll
      for (int nt = 0; nt < 4; ++nt) {
        int gc = bn * 128 + n0 + nt * 16 + l15;
        float d2 = nqv + nkv[nt] - 2.f * acc[mt][nt][reg];
        Dout[gr * 2048 + gc] = sqrtf(fmaxf(d2, 0.f));
      }
    }
}

// ---------------- fused conv1+conv2+conv3+residual, 6-wave blocks ----------------
// ROUND-9 LESSON: weights live in AGPRs (~160 unified regs/wave) -> 3 waves/SIMD
// is structural; a single 12-wave barrier domain/CU leaves ~41% of cycles with
// nothing issuing (r4-r9 all ~500us regardless of barriers/memory structure).
// THIS VERSION: 6-wave (384-thr) blocks, 30-px tiles -> TWO independent barrier
// domains per CU overlap each other's stalls. Role rotation (wv+bx+by)%6
// decorrelates class->SIMD so co-resident blocks balance conv2 load.
// Roles: 0-3 conv2 (mb=role&1, T2=role>>1), 4 conv1 (tiles 0,1), 5 conv3+conv1t2.
// Lags (r9-verified): conv1 writes act1(r); conv2 reads act1(r-1), emits
// act2(r-3) via 5-acc ring; conv3 reads act2(r-4), emits out y=r-5.
// No global ops in the row loop (r6); static register indices only (r3).
__global__ __launch_bounds__(384, 3) void fused_conv(
    const float* __restrict__ Dmat, const float* __restrict__ lq, const float* __restrict__ lk,
    const unsigned short* __restrict__ W1g, const unsigned short* __restrict__ W2g,
    const unsigned short* __restrict__ W3g,
    const float* __restrict__ b1, const float* __restrict__ b2, const float* __restrict__ b3,
    float* __restrict__ Sout) {
  __shared__ int4 a1s[288];        // [2][36][4] act1 ring, swizzled
  __shared__ int4 a2s[272];        // [2][34][4] act2 ring, swizzled
  __shared__ unsigned dps[2352];   // [42][56] DP tile (stride 56)
  __shared__ float dres[1024];     // [32][32] residual in, S out (in-place)
  const int t = threadIdx.x;
  const int wv = t >> 6, l = t & 63, l15 = l & 15, q4 = l >> 4;
  const int x0 = blockIdx.x * 30, y0 = blockIdx.y * 32;
  const int role = (wv + blockIdx.x + blockIdx.y) % 6;

  int4 uni[25];     // conv2: W2 frags | conv3: [0..5] shifts, [6..11] W1, [12..14] W3
  int4 uni2[6];     // conv2: acc ring[5] | conv1: W1 frags [mb*3+j]
  float bias4[4], bias4b[4];
  float bias3 = 0.f;
  const int mb = role & 1;
  const int T2 = role >> 1;

  if (role < 4) {
    const int4* W2i = (const int4*)W2g;
#pragma unroll
    for (int d = 0; d < 5; ++d)
#pragma unroll
      for (int s = 0; s < 5; ++s)
        uni[d * 5 + s] = W2i[(d * 32 + mb * 16 + l15) * 20 + s * 4 + q4];
#pragma unroll
    for (int j = 0; j < 5; ++j) uni2[j] = make_int4(0, 0, 0, 0);
#pragma unroll
    for (int i = 0; i < 4; ++i) {
      int ch = mb * 16 + q4 * 4 + i;
      bias4[i] = (ch < 30) ? b2[ch] : 0.f;
    }
  } else if (role == 4) {
    const int4* W1i = (const int4*)W1g;
#pragma unroll
    for (int m2 = 0; m2 < 2; ++m2)
#pragma unroll
      for (int j = 0; j < 3; ++j)
        uni2[m2 * 3 + j] = W1i[(j * 32 + m2 * 16 + l15) * 4 + q4];
#pragma unroll
    for (int i = 0; i < 4; ++i) {
      int ch0 = q4 * 4 + i, ch1 = 16 + q4 * 4 + i;
      bias4[i] = b1[ch0];
      bias4b[i] = (ch1 < 30) ? b1[ch1] : 0.f;
    }
  } else {
    const int4* W1i = (const int4*)W1g;
    const int4* W3i = (const int4*)W3g;
#pragma unroll
    for (int m2 = 0; m2 < 2; ++m2)
#pragma unroll
      for (int j = 0; j < 3; ++j)
        uni[6 + m2 * 3 + j] = W1i[(j * 32 + m2 * 16 + l15) * 4 + q4];
#pragma unroll
    for (int dx = 0; dx < 3; ++dx)
      uni[12 + dx] = (l15 < 3) ? W3i[(l15 * 3 + dx) * 4 + q4] : make_int4(0, 0, 0, 0);
#pragma unroll
    for (int j = 0; j < 6; ++j) uni[j] = make_int4(0, 0, 0, 0);
#pragma unroll
    for (int i = 0; i < 4; ++i) {
      int ch0 = q4 * 4 + i, ch1 = 16 + q4 * 4 + i;
      bias4[i] = b1[ch0];
      bias4b[i] = (ch1 < 30) ? b1[ch1] : 0.f;
    }
    bias3 = b3[0];
  }

  // ---- prologue: stage DP tile (pack D,P -> bf16 pair) ----
  for (int i = t; i < 2352; i += 384) {
    int row = i / 56, c = i - row * 56;
    int gy = y0 - 5 + row, gx = x0 - 5 + c;
    unsigned v = 0u;
    if (gy >= 0 && gy < 2048 && gx >= 0 && gx < 2048) {
      float Dv = Dmat[gy * 2048 + gx];
      float Pv = fabsf(lq[gy] - lk[gx]);
      v = (unsigned)f2bf(Dv) | ((unsigned)f2bf(Pv) << 16);
    }
    dps[i] = v;
  }
  // ---- prologue: stage residual rows ----
  for (int i = t; i < 1024; i += 384) {
    int row = i >> 5, ox = i & 31;
    int gx = x0 + ox;
    float dv = 0.f;
    if (ox < 30 && gx < 2048) dv = Dmat[(y0 + row) * 2048 + gx];
    dres[i] = dv;
  }
  // zero act2 pad px 32,33 (both ring slots)
  if (t < 16) {
    int sl = t >> 3, rem = t & 7;
    a2s[(sl * 34 + 32 + (rem >> 2)) * 4 + (rem & 3)] = make_int4(0, 0, 0, 0);
  }
  __syncthreads();

  for (int r = y0 - 3; r <= y0 + 36; ++r) {
    if (role < 4) {
      // ---- conv2: consume act1 row rc = r-1 (5-dy sliding accs) ----
      int rc = r - 1;
      if (rc >= y0 - 3 && rc <= y0 + 34) {
        int sl = rc & 1;
#pragma unroll
        for (int s = 0; s < 5; ++s) {
          int px = T2 * 16 + l15 + s;
          s8v B = as_s8(a1s[(sl * 36 + px) * 4 + (q4 ^ ((px >> 1) & 3))]);
#pragma unroll
          for (int d = 0; d < 5; ++d)
            uni2[4 - d] = as_i4(__builtin_amdgcn_mfma_f32_16x16x32_bf16(
                as_s8(uni[d * 5 + s]), B, as_f4(uni2[4 - d]), 0, 0, 0));
        }
      }
      // ---- emit act2 row r2c = r-3 (single bf16, swizzled) ----
      int r2c = r - 3;
      if (r2c >= y0 - 1 && r2c <= y0 + 32) {
        int px2 = T2 * 16 + l15;
        int gx2 = x0 - 1 + px2;
        bool ok = (r2c >= 0 && r2c < 2048 && gx2 >= 0 && gx2 < 2048);
        f4v a = as_f4(uni2[0]);
        ushort4 hv;
        hv.x = f2bf(ok ? fmaxf(a[0] + bias4[0], 0.f) : 0.f);
        hv.y = f2bf(ok ? fmaxf(a[1] + bias4[1], 0.f) : 0.f);
        hv.z = f2bf(ok ? fmaxf(a[2] + bias4[2], 0.f) : 0.f);
        hv.w = f2bf(ok ? fmaxf(a[3] + bias4[3], 0.f) : 0.f);
        int slot = (mb * 2 + (q4 >> 1)) ^ ((px2 >> 1) & 3);
        *(ushort4*)((unsigned short*)a2s + ((r2c & 1) * 34 + px2) * 32 + slot * 8 + (q4 & 1) * 4) = hv;
      }
#pragma unroll
      for (int j = 0; j < 4; ++j) uni2[j] = uni2[j + 1];
      uni2[4] = make_int4(0, 0, 0, 0);
    } else if (role == 4) {
      // ---- conv1 tiles 0,1 x both ch halves: produce act1 row r px 0..31 ----
      if (r >= y0 - 3 && r <= y0 + 34) {
        bool rowok = (r >= 0 && r < 2048);
#pragma unroll
        for (int T1 = 0; T1 < 2; ++T1) {
          int px = T1 * 16 + l15;
          int gx = x0 - 3 + px;
          bool ok = rowok && gx >= 0 && gx < 2048;
          int4 bi[3];
#pragma unroll
          for (int j = 0; j < 3; ++j) {
            int rlo = r - 2 + 2 * j;
            int rowsel = (j == 2) ? rlo : ((q4 < 2) ? rlo : (rlo + 1));
            int ri = rowsel - y0 + 5;
            bi[j] = *(const int4*)(dps + ri * 56 + px + (q4 & 1) * 4);
          }
#pragma unroll
          for (int m2 = 0; m2 < 2; ++m2) {
            f4v acc = {0.f, 0.f, 0.f, 0.f};
#pragma unroll
            for (int j = 0; j < 3; ++j)
              acc = __builtin_amdgcn_mfma_f32_16x16x32_bf16(as_s8(uni2[m2 * 3 + j]), as_s8(bi[j]), acc, 0, 0, 0);
            const float* bb = (m2 == 0) ? bias4 : bias4b;
            ushort4 sv;
            sv.x = f2bf(ok ? fmaxf(acc[0] + bb[0], 0.f) : 0.f);
            sv.y = f2bf(ok ? fmaxf(acc[1] + bb[1], 0.f) : 0.f);
            sv.z = f2bf(ok ? fmaxf(acc[2] + bb[2], 0.f) : 0.f);
            sv.w = f2bf(ok ? fmaxf(acc[3] + bb[3], 0.f) : 0.f);
            int slot = (m2 * 2 + (q4 >> 1)) ^ ((px >> 1) & 3);
            *(ushort4*)((unsigned short*)a1s + ((r & 1) * 36 + px) * 32 + slot * 8 + (q4 & 1) * 4) = sv;
          }
        }
      }
    } else {
      // ---- conv1 tile 2 (px 32..47, store px<36) x both ch halves ----
      if (r >= y0 - 3 && r <= y0 + 34) {
        bool rowok = (r >= 0 && r < 2048);
        int px = 32 + l15;
        int gx = x0 - 3 + px;
        bool ok = rowok && (px < 36) && gx < 2048;
        int4 bi[3];
#pragma unroll
        for (int j = 0; j < 3; ++j) {
          int rlo = r - 2 + 2 * j;
          int rowsel = (j == 2) ? rlo : ((q4 < 2) ? rlo : (rlo + 1));
          int ri = rowsel - y0 + 5;
          bi[j] = *(const int4*)(dps + ri * 56 + px + (q4 & 1) * 4);
        }
#pragma unroll
        for (int m2 = 0; m2 < 2; ++m2) {
          f4v acc = {0.f, 0.f, 0.f, 0.f};
#pragma unroll
          for (int j = 0; j < 3; ++j)
            acc = __builtin_amdgcn_mfma_f32_16x16x32_bf16(as_s8(uni[6 + m2 * 3 + j]), as_s8(bi[j]), acc, 0, 0, 0);
          const float* bb = (m2 == 0) ? bias4 : bias4b;
          ushort4 sv;
          sv.x = f2bf(ok ? fmaxf(acc[0] + bb[0], 0.f) : 0.f);
          sv.y = f2bf(ok ? fmaxf(acc[1] + bb[1], 0.f) : 0.f);
          sv.z = f2bf(ok ? fmaxf(acc[2] + bb[2], 0.f) : 0.f);
          sv.w = f2bf(ok ? fmaxf(acc[3] + bb[3], 0.f) : 0.f);
          if (px < 36) {
            int slot = (m2 * 2 + (q4 >> 1)) ^ ((px >> 1) & 3);
            *(ushort4*)((unsigned short*)a1s + ((r & 1) * 36 + px) * 32 + slot * 8 + (q4 & 1) * 4) = sv;
          }
        }
      }
      // ---- conv3: consume act2 row a = r-4 (m=dy trick, 3 MFMA per 16px) ----
      int a = r - 4;
      if (a >= y0 - 1 && a <= y0 + 32) {
        int sl = a & 1;
#pragma unroll
        for (int tt = 0; tt < 2; ++tt) {
          f4v acc3 = {0.f, 0.f, 0.f, 0.f};
#pragma unroll
          for (int dx = 0; dx < 3; ++dx) {
            int px2 = tt * 16 + l15 + dx;
            s8v B = as_s8(a2s[(sl * 34 + px2) * 4 + (q4 ^ ((px2 >> 1) & 3))]);
            acc3 = __builtin_amdgcn_mfma_f32_16x16x32_bf16(as_s8(uni[12 + dx]), B, acc3, 0, 0, 0);
          }
          uni[tt * 3 + 2] = as_i4(acc3);
        }
      }
      // ---- emit out row y = r-5 into dres ----
      int y = r - 5;
      if (y >= y0 && y <= y0 + 31) {
        int row = y - y0;
        if (q4 == 0) {
#pragma unroll
          for (int tt = 0; tt < 2; ++tt) {
            int ox = tt * 16 + l15;
            float val = as_f4(uni[tt * 3 + 0])[0] + as_f4(uni[tt * 3 + 1])[1]
                      + as_f4(uni[tt * 3 + 2])[2] + bias3 + dres[row * 32 + ox];
            if (ox < 30) dres[row * 32 + ox] = val;
          }
        }
      }
      // shift conv3 accs (static moves)
#pragma unroll
      for (int tt = 0; tt < 2; ++tt) {
        uni[tt * 3 + 0] = uni[tt * 3 + 1];
        uni[tt * 3 + 1] = uni[tt * 3 + 2];
      }
    }
    __syncthreads();
  }

  // ---- epilogue: cooperative store of S tile ----
  for (int i = t; i < 1024; i += 384) {
    int row = i >> 5, ox = i & 31;
    int gx = x0 + ox;
    if (ox < 30 && gx < 2048) Sout[(y0 + row) * 2048 + gx] = dres[i];
  }
}

// ---------------- row softmax (in-place on d_out) + dis accumulation ----------------
__global__ __launch_bounds__(256) void softmax_kernel(
    float* __restrict__ S, const float* __restrict__ Dmat, float* __restrict__ accum) {
  const int row = blockIdx.x, t = threadIdx.x;
  float* Srow = S + row * 2048;
  const float* Drow = Dmat + row * 2048;
  float sv[8], dv[8];
  float mx = -1e30f;
#pragma unroll
  for (int i = 0; i < 8; ++i) {
    sv[i] = -Srow[t + i * 256];
    dv[i] = Drow[t + i * 256];
    mx = fmaxf(mx, sv[i]);
  }
  __shared__ float red[4], redz[4], redw[4];
  for (int off = 32; off; off >>= 1) mx = fmaxf(mx, __shfl_xor(mx, off));
  const int wv = t >> 6, l = t & 63;
  if (l == 0) red[wv] = mx;
  __syncthreads();
  mx = fmaxf(fmaxf(red[0], red[1]), fmaxf(red[2], red[3]));
  float z = 0.f, w = 0.f, ev[8];
#pragma unroll
  for (int i = 0; i < 8; ++i) {
    ev[i] = __expf(sv[i] - mx);
    z += ev[i];
    w += ev[i] * dv[i];
  }
  for (int off = 32; off; off >>= 1) { z += __shfl_xor(z, off); w += __shfl_xor(w, off); }
  if (l == 0) { redz[wv] = z; redw[wv] = w; }
  __syncthreads();
  z = redz[0] + redz[1] + redz[2] + redz[3];
  w = redw[0] + redw[1] + redw[2] + redw[3];
  float inv = 1.f / z;
#pragma unroll
  for (int i = 0; i < 8; ++i) Srow[t + i * 256] = ev[i] * inv;
  if (t == 0) atomicAdd(accum, w * inv);
}

__global__ void finalize_kernel(const float* __restrict__ accum, float* __restrict__ out) {
  if (threadIdx.x == 0) out[0] = accum[0] * (1.f / 2048.f);
}

// ---------------- host ----------------
extern "C" void kernel_launch(void* const* d_in, const int* in_sizes, int n_in,
                              void* d_out, int out_size, void* d_ws, size_t ws_size,
                              hipStream_t stream) {
  const float* seq_q = (const float*)d_in[0];
  const float* seq_k = (const float*)d_in[1];
  const float* len_q = (const float*)d_in[2];
  const float* len_k = (const float*)d_in[3];
  const float* w1 = (const float*)d_in[4];
  const float* b1 = (const float*)d_in[5];
  const float* w2 = (const float*)d_in[6];
  const float* b2 = (const float*)d_in[7];
  const float* w3 = (const float*)d_in[8];
  const float* b3 = (const float*)d_in[9];

  char* ws = (char*)d_ws;
  unsigned short* Qb  = (unsigned short*)(ws);                         // 2 MiB
  unsigned short* Kb  = (unsigned short*)(ws + ((size_t)2 << 20));     // 2 MiB
  float* nq           = (float*)(ws + ((size_t)4 << 20));              // 8 KiB
  float* nk           = (float*)(ws + ((size_t)4 << 20) + 16384);
  unsigned short* W1  = (unsigned short*)(ws + ((size_t)4 << 20) + 32768);   // 6 KiB (packed)
  unsigned short* W2  = (unsigned short*)(ws + ((size_t)4 << 20) + 65536);   // 50 KiB
  unsigned short* W3  = (unsigned short*)(ws + ((size_t)4 << 20) + 131072);  // 576 B
  float* accum        = (float*)(ws + ((size_t)4 << 20) + 163840);
  float* Dmat         = (float*)(ws + ((size_t)5 << 20));              // 16 MiB fp32
  float* out = (float*)d_out;

  const int prep_total = 2 * 2048 * 512 + 3072 + 25600 + 288 + 1;
  prep_kernel<<<(prep_total + 255) / 256, 256, 0, stream>>>(
      seq_q, seq_k, w1, w2, w3, Qb, Kb, W1, W2, W3, accum);
  norms_kernel<<<1024, 256, 0, stream>>>(seq_q, seq_k, nq, nk);
  dgemm_kernel<<<dim3(16, 16), 256, 0, stream>>>(Qb, Kb, nq, nk, Dmat);
  fused_conv<<<dim3(69, 64), 384, 0, stream>>>(
      Dmat, len_q, len_k, W1, W2, W3, b1, b2, b3, out);
  softmax_kernel<<<2048, 256, 0, stream>>>(out, Dmat, accum);
  finalize_kernel<<<1, 64, 0, stream>>>(accum, out + 4194304);
}